// Round 1
// baseline (765.848 us; speedup 1.0000x reference)
//
#include <hip/hip_runtime.h>
#include <cstdint>
#include <cstddef>

// Problem constants (B=1, S=65536, D=1024, P=512, E=3, C=2)
#define T_TOK 65536
#define DDIM  1024
#define PDIM  512

typedef __attribute__((ext_vector_type(8))) short          shortx8;
typedef __attribute__((ext_vector_type(8))) unsigned short ushortx8;
typedef __attribute__((ext_vector_type(4))) float          floatx4;

__device__ __forceinline__ unsigned short f2bf_rn(float x){
  unsigned int u = __float_as_uint(x);
  unsigned int r = u + 0x7FFFu + ((u >> 16) & 1u);
  return (unsigned short)(r >> 16);
}
__device__ __forceinline__ float bf2f(unsigned short h){
  return __uint_as_float(((unsigned int)h) << 16);
}
// fast tanh, NaN-safe at +-inf of exp
__device__ __forceinline__ float ftanh(float x){
  float ez = __expf(2.f * x);
  return 1.f - 2.f / (ez + 1.f);
}

__device__ __forceinline__ void gload16(const void* g, void* l){
  __builtin_amdgcn_global_load_lds(
      (const __attribute__((address_space(1))) unsigned int*)g,
      (__attribute__((address_space(3))) unsigned int*)l, 16, 0, 0);
}
__device__ __forceinline__ void bar(){
  asm volatile("" ::: "memory");
  __builtin_amdgcn_s_barrier();
  asm volatile("" ::: "memory");
}
#define WAIT_VMC(n) asm volatile("s_waitcnt vmcnt(" #n ")" ::: "memory")
#define WAIT_LGKM0  do { asm volatile("s_waitcnt lgkmcnt(0)" ::: "memory"); \
                         __builtin_amdgcn_sched_barrier(0); } while(0)

// split two float4 (8 consecutive k) into hi/lo bf16 granules (truncation hi,
// exact residual lo) -- matches the MFMA 3-term scheme (hh + lh + hl).
__device__ __forceinline__ void split2(const float4 a, const float4 b,
                                       ushortx8* hi, ushortx8* lo){
  float vs[8] = {a.x, a.y, a.z, a.w, b.x, b.y, b.z, b.w};
  ushortx8 h, l;
  #pragma unroll
  for (int j = 0; j < 8; j++){
    unsigned int u = __float_as_uint(vs[j]);
    float r = vs[j] - __uint_as_float(u & 0xFFFF0000u);
    h[j] = (unsigned short)(u >> 16);
    l[j] = (unsigned short)(__float_as_uint(r) >> 16);
  }
  *hi = h; *lo = l;
}

// ---------------------------------------------------------------------------
// prep: zero [hist1 3x4096 | h2 3x2048 | params 64 | bagsum 512 | aggsum 512
//             | mf 1024]  (20544 ints).
// B weights are split to bf16 hi/lo AND re-tiled into the per-(K-tile,
// n-block) swizzled layout the GEMM's linear global_load_lds staging expects:
//   Bt[tb=kt*2+nb][row 0..255][slot s 0..3][e 0..7]
//     = B[nb*256+row][kt*32 + ((s ^ (row&3))<<3) + e]   (B[n][k] = W[k][n])
// so that LDS granule (row, s) holds k-granule (s ^ (row&3)) -> the XOR-
// swizzled ds_read_b128 (slot = quad ^ (row&3)) recovers k-granule quad.
// ---------------------------------------------------------------------------
__global__ void prep(const float* __restrict__ Wt1, const float* __restrict__ Wa1,
                     unsigned short* __restrict__ W1th, unsigned short* __restrict__ W1tl,
                     unsigned short* __restrict__ Wath, unsigned short* __restrict__ Watl,
                     int* __restrict__ zbase)
{
  int gid = blockIdx.x * 256 + threadIdx.x;
  if (gid < 20544){ zbase[gid] = 0; return; }
  int i = gid - 20544;
  if (i < 524288){
    int e   = i & 7;
    int g16 = i >> 3;
    int s   = g16 & 3;
    int row = (g16 >> 2) & 255;
    int tb  = g16 >> 10;            // kt*2 + nb, kt < 32
    int nb  = tb & 1, kt = tb >> 1;
    int n = nb * 256 + row;
    int k = kt * 32 + ((s ^ (row & 3)) << 3) + e;
    float x = Wt1[(size_t)k * PDIM + n];
    unsigned short h = f2bf_rn(x);
    W1th[i] = h;
    W1tl[i] = f2bf_rn(x - bf2f(h));
    return;
  }
  i -= 524288;
  if (i < 262144){
    int e   = i & 7;
    int g16 = i >> 3;
    int s   = g16 & 3;
    int row = (g16 >> 2) & 255;
    int tb  = g16 >> 10;            // kt*2 + nb, kt < 16
    int nb  = tb & 1, kt = tb >> 1;
    int n = nb * 256 + row;
    int k = kt * 32 + ((s ^ (row & 3)) << 3) + e;
    float x = Wa1[(size_t)k * PDIM + n];
    unsigned short h = f2bf_rn(x);
    Wath[i] = h;
    Watl[i] = f2bf_rn(x - bf2f(h));
  }
}

// ---------------------------------------------------------------------------
// Split-bf16 GEMM, 256x256 tile, BK=32, 512 threads (8 waves as 2x4;
// per-wave 128x64 output, 8x4 16x16 accumulators).
// 4-phase pipelined K-loop (T3+T4): per phase {ds_read subtile | stage-issue;
// barrier; lgkmcnt(0); setprio(1); 24 MFMA; setprio(0); barrier}. Counted
// vmcnt(4) at phase 2 (A regs), vmcnt(0) only at phase 3 (B gload_lds) --
// prefetch loads stay in flight across barriers. Double-buffered 128 KiB LDS
// with 16B-granule XOR swizzle (slot = g ^ (row&3)) on both write and read.
// A (fp32) is reg-staged (issue-early at phase 0, split+ds_write at phase 2);
// B (pre-split, pre-tiled, inverse-swizzled by prep) streams via linear
// global_load_lds_dwordx4.
// MODE 0: store tanh(C) (patches); column sums -> atomicAdd colacc (bag).
// MODE 1: rows via cidx (compacted union), weighted column sums (agg).
// ---------------------------------------------------------------------------
template<int MODE>
__global__ __launch_bounds__(512, 2)
void gemm_split(const float* __restrict__ A,
                const unsigned short* __restrict__ Bhg,
                const unsigned short* __restrict__ Blg,
                float* __restrict__ Cout,
                float* __restrict__ colacc,
                const int* __restrict__ cidx,
                const float* __restrict__ wgt,
                const int* __restrict__ params)
{
  constexpr int K  = (MODE == 0) ? 1024 : 512;
  constexpr int NT = K >> 5;

  __shared__ unsigned short AhL[2][8192];
  __shared__ unsigned short AlL[2][8192];
  __shared__ unsigned short BhL[2][8192];
  __shared__ unsigned short BlL[2][8192];
  __shared__ int   cidxl[256];
  __shared__ float wl[256];

  const int tid = threadIdx.x;
  const int d = blockIdx.x + (blockIdx.y << 1);
  // MODE 0: XCD-bijective swizzle (512 % 8 == 0) so both column-blocks of a
  // row-panel land on the same XCD consecutively (A-panel L2 reuse).
  // MODE 1: natural order -- active blocks are the low indices; swizzling
  // would concentrate them on a few XCDs.
  const int lin = (MODE == 0) ? (((d & 7) << 6) + (d >> 3)) : d;
  const int bx = lin & 1, by = lin >> 1;
  const int m0 = by << 8, n0 = bx << 8;

  if (MODE == 1){
    const int count = params[21];
    if (m0 >= count) return;
    if (tid < 256){
      int g = m0 + tid;
      if (g < count){ cidxl[tid] = cidx[g]; wl[tid] = wgt[g]; }
      else          { cidxl[tid] = 0;       wl[tid] = 0.f;   }
    }
    __syncthreads();
  }

  const int lane = tid & 63;
  const int wv   = tid >> 6;
  const int wm   = wv >> 2;          // 0..1  (m wave row)
  const int wn   = wv & 3;           // 0..3  (n wave col)
  const int lr   = lane & 15, quad = lane >> 4;
  const int sq   = (quad ^ (lr & 3)) << 4;      // swizzled 16B slot (reads)

  const int abase = (wm * 128 + lr) * 64 + sq;  // + mt*1024
  const int bbase = (wn * 64  + lr) * 64 + sq;  // + nt*1024

  // A staging: thread -> (row, half); 2 threads cover one row's 32 fp32.
  const int rowW = tid >> 1, half = tid & 1;
  const size_t arowg = (MODE == 0) ? (size_t)(m0 + rowW) : (size_t)cidxl[rowW];
  const float* ap = A + arowg * K + half * 16;
  const int wb0 = rowW * 64 + ((( half * 2     ) ^ (rowW & 3)) << 4);
  const int wb1 = rowW * 64 + ((( half * 2 + 1 ) ^ (rowW & 3)) << 4);

  floatx4 acc[8][4];
  #pragma unroll
  for (int i = 0; i < 8; i++)
    #pragma unroll
    for (int j = 0; j < 4; j++)
      acc[i][j] = (floatx4){0.f, 0.f, 0.f, 0.f};

  float4 av0, av1, av2, av3;

  // ---- prologue: fully stage tile 0 into buffer 0
  {
    av0 = *(const float4*)(ap + 0);
    av1 = *(const float4*)(ap + 4);
    av2 = *(const float4*)(ap + 8);
    av3 = *(const float4*)(ap + 12);
    const size_t tb = (size_t)bx * 8192;        // kt = 0
    gload16(Bhg + tb + tid * 8,        (char*)BhL[0] + tid * 16);
    gload16(Bhg + tb + 4096 + tid * 8, (char*)BhL[0] + 8192 + tid * 16);
    gload16(Blg + tb + tid * 8,        (char*)BlL[0] + tid * 16);
    gload16(Blg + tb + 4096 + tid * 8, (char*)BlL[0] + 8192 + tid * 16);
    WAIT_VMC(4);                                 // A loads done (oldest 4)
    ushortx8 h, l;
    split2(av0, av1, &h, &l);
    *(ushortx8*)((char*)AhL[0] + wb0) = h;
    *(ushortx8*)((char*)AlL[0] + wb0) = l;
    split2(av2, av3, &h, &l);
    *(ushortx8*)((char*)AhL[0] + wb1) = h;
    *(ushortx8*)((char*)AlL[0] + wb1) = l;
    WAIT_VMC(0);                                 // B gload_lds done
    asm volatile("s_waitcnt lgkmcnt(0)" ::: "memory");  // ds_writes drained
    bar();
  }

  #pragma unroll 2
  for (int t = 0; t < NT; ++t){
    const int cur = t & 1, nxt = cur ^ 1;
    const int kn = (t + 1 < NT) ? (t + 1) : t;   // clamped prefetch index
    const char* AhC = (const char*)AhL[cur];
    const char* AlC = (const char*)AlL[cur];
    const char* BhC = (const char*)BhL[cur];
    const char* BlC = (const char*)BlL[cur];

    shortx8 aH[4], aL[4], bH0[2], bL0[2], bH1[2], bL1[2];

    // ---- phase 0: reads A m-half0 + B n-half0; issue next A global loads
    #pragma unroll
    for (int mt = 0; mt < 4; mt++){
      aH[mt] = *(const shortx8*)(AhC + abase + mt * 1024);
      aL[mt] = *(const shortx8*)(AlC + abase + mt * 1024);
    }
    #pragma unroll
    for (int nt = 0; nt < 2; nt++){
      bH0[nt] = *(const shortx8*)(BhC + bbase + nt * 1024);
      bL0[nt] = *(const shortx8*)(BlC + bbase + nt * 1024);
    }
    {
      const float* apk = ap + kn * 32;
      av0 = *(const float4*)(apk);
      av1 = *(const float4*)(apk + 4);
      av2 = *(const float4*)(apk + 8);
      av3 = *(const float4*)(apk + 12);
    }
    bar();
    WAIT_LGKM0;
    __builtin_amdgcn_s_setprio(1);
    #pragma unroll
    for (int mt = 0; mt < 4; mt++)
      #pragma unroll
      for (int nt = 0; nt < 2; nt++){
        acc[mt][nt] = __builtin_amdgcn_mfma_f32_16x16x32_bf16(aH[mt], bH0[nt], acc[mt][nt], 0, 0, 0);
        acc[mt][nt] = __builtin_amdgcn_mfma_f32_16x16x32_bf16(aL[mt], bH0[nt], acc[mt][nt], 0, 0, 0);
        acc[mt][nt] = __builtin_amdgcn_mfma_f32_16x16x32_bf16(aH[mt], bL0[nt], acc[mt][nt], 0, 0, 0);
      }
    __builtin_amdgcn_s_setprio(0);
    bar();

    // ---- phase 1: reads B n-half1; issue next B global_load_lds -> nxt
    #pragma unroll
    for (int nt = 0; nt < 2; nt++){
      bH1[nt] = *(const shortx8*)(BhC + bbase + (2 + nt) * 1024);
      bL1[nt] = *(const shortx8*)(BlC + bbase + (2 + nt) * 1024);
    }
    {
      const size_t tb = (size_t)(kn * 2 + bx) * 8192;
      gload16(Bhg + tb + tid * 8,        (char*)BhL[nxt] + tid * 16);
      gload16(Bhg + tb + 4096 + tid * 8, (char*)BhL[nxt] + 8192 + tid * 16);
      gload16(Blg + tb + tid * 8,        (char*)BlL[nxt] + tid * 16);
      gload16(Blg + tb + 4096 + tid * 8, (char*)BlL[nxt] + 8192 + tid * 16);
    }
    bar();
    WAIT_LGKM0;
    __builtin_amdgcn_s_setprio(1);
    #pragma unroll
    for (int mt = 0; mt < 4; mt++)
      #pragma unroll
      for (int nt = 0; nt < 2; nt++){
        acc[mt][2 + nt] = __builtin_amdgcn_mfma_f32_16x16x32_bf16(aH[mt], bH1[nt], acc[mt][2 + nt], 0, 0, 0);
        acc[mt][2 + nt] = __builtin_amdgcn_mfma_f32_16x16x32_bf16(aL[mt], bH1[nt], acc[mt][2 + nt], 0, 0, 0);
        acc[mt][2 + nt] = __builtin_amdgcn_mfma_f32_16x16x32_bf16(aH[mt], bL1[nt], acc[mt][2 + nt], 0, 0, 0);
      }
    __builtin_amdgcn_s_setprio(0);
    bar();

    // ---- phase 2: reads A m-half1; wait A regs; split + ds_write -> nxt
    #pragma unroll
    for (int mt = 0; mt < 4; mt++){
      aH[mt] = *(const shortx8*)(AhC + abase + (4 + mt) * 1024);
      aL[mt] = *(const shortx8*)(AlC + abase + (4 + mt) * 1024);
    }
    WAIT_VMC(4);                                 // next-A regs landed
    {
      ushortx8 h, l;
      split2(av0, av1, &h, &l);
      *(ushortx8*)((char*)AhL[nxt] + wb0) = h;
      *(ushortx8*)((char*)AlL[nxt] + wb0) = l;
      split2(av2, av3, &h, &l);
      *(ushortx8*)((char*)AhL[nxt] + wb1) = h;
      *(ushortx8*)((char*)AlL[nxt] + wb1) = l;
    }
    bar();
    WAIT_LGKM0;                                  // drains reads AND ds_writes
    __builtin_amdgcn_s_setprio(1);
    #pragma unroll
    for (int mt = 0; mt < 4; mt++)
      #pragma unroll
      for (int nt = 0; nt < 2; nt++){
        acc[4 + mt][nt] = __builtin_amdgcn_mfma_f32_16x16x32_bf16(aH[mt], bH0[nt], acc[4 + mt][nt], 0, 0, 0);
        acc[4 + mt][nt] = __builtin_amdgcn_mfma_f32_16x16x32_bf16(aL[mt], bH0[nt], acc[4 + mt][nt], 0, 0, 0);
        acc[4 + mt][nt] = __builtin_amdgcn_mfma_f32_16x16x32_bf16(aH[mt], bL0[nt], acc[4 + mt][nt], 0, 0, 0);
      }
    __builtin_amdgcn_s_setprio(0);
    bar();

    // ---- phase 3: wait next-B gload_lds; last MFMA quadrant
    WAIT_VMC(0);
    bar();
    WAIT_LGKM0;
    __builtin_amdgcn_s_setprio(1);
    #pragma unroll
    for (int mt = 0; mt < 4; mt++)
      #pragma unroll
      for (int nt = 0; nt < 2; nt++){
        acc[4 + mt][2 + nt] = __builtin_amdgcn_mfma_f32_16x16x32_bf16(aH[mt], bH1[nt], acc[4 + mt][2 + nt], 0, 0, 0);
        acc[4 + mt][2 + nt] = __builtin_amdgcn_mfma_f32_16x16x32_bf16(aL[mt], bH1[nt], acc[4 + mt][2 + nt], 0, 0, 0);
        acc[4 + mt][2 + nt] = __builtin_amdgcn_mfma_f32_16x16x32_bf16(aH[mt], bL1[nt], acc[4 + mt][2 + nt], 0, 0, 0);
      }
    __builtin_amdgcn_s_setprio(0);
    bar();
  }

  // epilogue: tanh, optional store / weighting, column sums -> global atomics
  float csum[4] = {0.f, 0.f, 0.f, 0.f};
  #pragma unroll
  for (int mt = 0; mt < 8; mt++){
    float w0 = 1.f, w1 = 1.f, w2 = 1.f, w3 = 1.f;
    if (MODE == 1){
      const float4 wv4 = *(const float4*)&wl[wm * 128 + mt * 16 + (quad << 2)];
      w0 = wv4.x; w1 = wv4.y; w2 = wv4.z; w3 = wv4.w;
    }
    #pragma unroll
    for (int nt = 0; nt < 4; nt++){
      float t0 = ftanh(acc[mt][nt][0]);
      float t1 = ftanh(acc[mt][nt][1]);
      float t2 = ftanh(acc[mt][nt][2]);
      float t3 = ftanh(acc[mt][nt][3]);
      if (MODE == 0){
        size_t base = (size_t)(m0 + wm * 128 + mt * 16 + (quad << 2)) * PDIM
                    + (n0 + wn * 64 + nt * 16 + lr);
        Cout[base]            = t0;
        Cout[base +     PDIM] = t1;
        Cout[base + 2 * PDIM] = t2;
        Cout[base + 3 * PDIM] = t3;
        csum[nt] += t0 + t1 + t2 + t3;
      } else {
        csum[nt] += t0 * w0 + t1 * w1 + t2 * w2 + t3 * w3;
      }
    }
  }
  #pragma unroll
  for (int nt = 0; nt < 4; nt++){
    float s = csum[nt];
    s += __shfl_xor(s, 16);
    s += __shfl_xor(s, 32);
    if (lane < 16) atomicAdd(&colacc[n0 + wn * 64 + nt * 16 + lane], s);
  }
}

// ---------------------------------------------------------------------------
// gates: per-token 3 gate GEMVs (fp32), router_logits out, w_top0 key, masks,
// per-expert counts, 4096-bin level-1 histograms (mantissa bits [22:11]).
// ---------------------------------------------------------------------------
__global__ void gates_kernel(const float* __restrict__ patches,
                             const float* __restrict__ Wg0,
                             const float* __restrict__ Wg1,
                             const float* __restrict__ Wg2,
                             float* __restrict__ dout,
                             unsigned int* __restrict__ wkey,
                             unsigned char* __restrict__ mask3,
                             int* __restrict__ params,
                             int* __restrict__ hist)
{
  __shared__ int lc[3];
  const int tid = threadIdx.x;
  if (tid < 3) lc[tid] = 0;
  __syncthreads();
  const int lane = tid & 63;
  float wg[3][16];
  const float* Wgp[3] = {Wg0, Wg1, Wg2};
  #pragma unroll
  for (int g = 0; g < 3; g++){
    #pragma unroll
    for (int j = 0; j < 4; j++){
      float4 v = *(const float4*)(Wgp[g] + lane * 16 + j * 4);
      wg[g][j * 4 + 0] = v.x; wg[g][j * 4 + 1] = v.y;
      wg[g][j * 4 + 2] = v.z; wg[g][j * 4 + 3] = v.w;
    }
  }
  const int nw = gridDim.x << 2;
  for (int t = blockIdx.x * 4 + (tid >> 6); t < T_TOK; t += nw){
    const float* row = patches + (size_t)t * PDIM + lane * 8;
    float4 v0 = *(const float4*)row;
    float4 v1 = *(const float4*)(row + 4);
    float x[8] = {v0.x, v0.y, v0.z, v0.w, v1.x, v1.y, v1.z, v1.w};
    float g00 = 0, g01 = 0, g10 = 0, g11 = 0, g20 = 0, g21 = 0;
    #pragma unroll
    for (int j = 0; j < 8; j++){
      g00 += x[j] * wg[0][2 * j]; g01 += x[j] * wg[0][2 * j + 1];
      g10 += x[j] * wg[1][2 * j]; g11 += x[j] * wg[1][2 * j + 1];
      g20 += x[j] * wg[2][2 * j]; g21 += x[j] * wg[2][2 * j + 1];
    }
    #pragma unroll
    for (int off = 1; off < 64; off <<= 1){
      g00 += __shfl_xor(g00, off); g01 += __shfl_xor(g01, off);
      g10 += __shfl_xor(g10, off); g11 += __shfl_xor(g11, off);
      g20 += __shfl_xor(g20, off); g21 += __shfl_xor(g21, off);
    }
    if (lane == 0){
      dout[8 + 2 * t]     = g00;
      dout[8 + 2 * t + 1] = g01;
      int m0 = g01 > g00;
      int m1 = g11 > g10;
      int m2 = g21 > g20;
      mask3[t] = (unsigned char)(m0 | (m1 << 1) | (m2 << 2));
      float d = fabsf(g00 - g01);
      float w = 1.0f / (1.0f + __expf(-d));   // top-1 softmax prob in [0.5,1)
      unsigned int u = __float_as_uint(w);
      u = u < 0x3F000000u ? 0x3F000000u : u;
      u = u > 0x3F7FFFFFu ? 0x3F7FFFFFu : u;
      wkey[t] = u;
      int b = (int)((u >> 11) & 0xFFFu);      // mantissa bits [22:11]
      if (m0){ atomicAdd(&hist[b], 1);         atomicAdd(&lc[0], 1); }
      if (m1){ atomicAdd(&hist[4096 + b], 1);  atomicAdd(&lc[1], 1); }
      if (m2){ atomicAdd(&hist[8192 + b], 1);  atomicAdd(&lc[2], 1); }
    }
  }
  __syncthreads();
  if (tid < 3 && lc[tid]) atomicAdd(&params[tid], lc[tid]);
}

// ---------------------------------------------------------------------------
// find_bucket: nums = floor(cnt*frac) via shifts; locate 12-bit bucket of
// the nums-th largest key (suffix scan over 4096 bins).
// params: [0..2] cnt [3..5] nums [6..8] bucket [9..11] rank-in-bucket
//         [12..14] theta_u [15..17] r_ties [18..20] c_eq [21] compact count
// ---------------------------------------------------------------------------
__global__ void find_bucket(int* __restrict__ params, const int* __restrict__ hist)
{
  __shared__ int cs[256], orig[256];
  __shared__ int selc, selrk;
  const int tid = threadIdx.x;
  for (int e = 0; e < 3; e++){
    int cnt = params[e];
    int shift = (e == 1) ? 1 : 2;              // FRACS 0.25,0.5,0.25 exact
    int nums = cnt >> shift;
    if (nums == 0) nums = cnt;
    if (tid == 0) params[3 + e] = nums;
    __syncthreads();
    if (nums == 0){
      if (tid == 0){ params[6 + e] = -1; params[9 + e] = 0; }
      __syncthreads();
      continue;
    }
    const int* h = hist + e * 4096 + tid * 16;
    int s = 0;
    #pragma unroll
    for (int j = 0; j < 16; j++) s += h[j];
    cs[tid] = s; orig[tid] = s;
    __syncthreads();
    for (int off = 1; off < 256; off <<= 1){
      int v = (tid + off < 256) ? cs[tid + off] : 0;
      __syncthreads();
      cs[tid] += v;
      __syncthreads();
    }
    if (cs[tid] >= nums && (cs[tid] - orig[tid]) < nums){
      selc = tid; selrk = nums - (cs[tid] - orig[tid]);
    }
    __syncthreads();
    if (tid == 0){
      int ch = selc, rk = selrk;
      const int* hh = hist + e * 4096 + ch * 16;
      int acc = 0;
      for (int j = 15; j >= 0; j--){
        int c = hh[j];
        if (acc + c >= rk){ params[6 + e] = ch * 16 + j; params[9 + e] = rk - acc; break; }
        acc += c;
      }
    }
    __syncthreads();
  }
}

// ---------------------------------------------------------------------------
// level2hist: 2048-bin histogram (mantissa bits [10:0]) of keys within the
// chosen bucket. grid (32,3), global atomics.
// ---------------------------------------------------------------------------
__global__ void level2hist(const int* __restrict__ params, const unsigned int* __restrict__ wkey,
                           const unsigned char* __restrict__ mask3, int* __restrict__ h2)
{
  const int e = blockIdx.y;
  const int B = params[6 + e];
  if (B < 0) return;
  const unsigned char bit = (unsigned char)(1u << e);
  const int t0 = blockIdx.x * 2048 + threadIdx.x;
  #pragma unroll
  for (int i = 0; i < 8; i++){
    int t = t0 + i * 256;
    if (mask3[t] & bit){
      unsigned int u = wkey[t];
      if ((int)((u >> 11) & 0xFFFu) == B) atomicAdd(&h2[e * 2048 + (u & 2047u)], 1);
    }
  }
}

// ---------------------------------------------------------------------------
// find_theta: exact threshold key (bucket + sub-bin = all 23 mantissa bits),
// ties-to-take r, tie count c_eq. grid = 3 blocks.
// ---------------------------------------------------------------------------
__global__ void find_theta(int* __restrict__ params, const int* __restrict__ h2)
{
  const int e = blockIdx.x;
  const int tid = threadIdx.x;
  __shared__ int cs[256], orig[256];
  __shared__ int selc;
  int B = params[6 + e], rank = params[9 + e];
  if (B < 0){
    if (tid == 0){ params[12 + e] = (int)0xFFFFFFFFu; params[15 + e] = 0; params[18 + e] = 0; }
    return;
  }
  const int* h = h2 + e * 2048 + tid * 8;
  int s = 0;
  #pragma unroll
  for (int j = 0; j < 8; j++) s += h[j];
  cs[tid] = s; orig[tid] = s;
  __syncthreads();
  for (int off = 1; off < 256; off <<= 1){
    int v = (tid + off < 256) ? cs[tid + off] : 0;
    __syncthreads();
    cs[tid] += v;
    __syncthreads();
  }
  if (cs[tid] >= rank && (cs[tid] - orig[tid]) < rank) selc = tid;
  __syncthreads();
  if (tid == 0){
    int ch = selc;
    int rk = rank - (cs[ch] - orig[ch]);
    const int* hh = h2 + e * 2048 + ch * 8;
    int acc = 0;
    for (int j = 7; j >= 0; j--){
      int c = hh[j];
      if (acc + c >= rk){
        int sub = ch * 8 + j;
        params[12 + e] = (int)(0x3F000000u | ((unsigned)B << 11) | (unsigned)sub);
        params[15 + e] = rk - acc;
        params[18 + e] = c;
        break;
      }
      acc += c;
    }
  }
}

// ---------------------------------------------------------------------------
// mark_sel: sel = mask & (key>theta || (key==theta && tie-rank<r)).
// Fast path when all ties taken; slow stable index-ordered path otherwise.
// ---------------------------------------------------------------------------
__global__ void mark_sel(const int* __restrict__ params, const unsigned int* __restrict__ wkey,
                         const unsigned char* __restrict__ mask3, unsigned char* __restrict__ selb)
{
  const int e = blockIdx.y;
  const int bx = blockIdx.x;
  const int tid = threadIdx.x;
  const unsigned int theta = (unsigned int)params[12 + e];
  const int r = params[15 + e];
  const int ceq = params[18 + e];
  const unsigned char bit = (unsigned char)(1u << e);
  unsigned char* sb = selb + e * T_TOK;
  if (ceq == r){
    int t0 = bx * 2048;
    #pragma unroll
    for (int i = 0; i < 8; i++){
      int t = t0 + i * 256 + tid;
      unsigned char mk = mask3[t] & bit;
      sb[t] = (mk && wkey[t] >= theta) ? 1 : 0;
    }
  } else {
    if (bx) return;
    __shared__ int basec;
    __shared__ int wsum[4];
    if (tid == 0) basec = 0;
    __syncthreads();
    const int lane = tid & 63, w = tid >> 6;
    for (int c = 0; c < 256; c++){
      int t = c * 256 + tid;
      unsigned char mk = mask3[t] & bit;
      unsigned int u = mk ? wkey[t] : 0u;
      bool gt = mk && (u > theta);
      bool eq = mk && (u == theta);
      unsigned long long bal = __ballot(eq);
      if (lane == 0) wsum[w] = __popcll(bal);
      __syncthreads();
      int wbase = 0;
      for (int ww = 0; ww < w; ww++) wbase += wsum[ww];
      int pos = basec + wbase + __popcll(bal & ((1ull << lane) - 1ull));
      sb[t] = (gt || (eq && pos < r)) ? 1 : 0;
      __syncthreads();
      if (tid == 0) basec += wsum[0] + wsum[1] + wsum[2] + wsum[3];
      __syncthreads();
    }
  }
}

// ---------------------------------------------------------------------------
// compact: list of tokens with total_sel>0 (order irrelevant for the sums),
// with float multiplicity weight. Count in params[21].
// ---------------------------------------------------------------------------
__global__ void compact(const unsigned char* __restrict__ selb, int* __restrict__ cidx,
                        float* __restrict__ wgt, int* __restrict__ params)
{
  int t = blockIdx.x * 256 + threadIdx.x;
  int ts = selb[t] + selb[T_TOK + t] + selb[2 * T_TOK + t];
  int lane = threadIdx.x & 63;
  unsigned long long bal = __ballot(ts > 0);
  int base = 0;
  if (lane == 0) base = atomicAdd(&params[21], __popcll(bal));
  base = __shfl(base, 0);
  if (ts){
    int pos = base + __popcll(bal & ((1ull << lane) - 1ull));
    cidx[pos] = t;
    wgt[pos] = (float)ts;
  }
}

// ---------------------------------------------------------------------------
// meanfeat_c: column sums of patches over sel0 / sel1 rows (experts 0,1 only;
// expert 2's mean_feat is unused). Runs over the compacted union list.
// ---------------------------------------------------------------------------
__global__ void meanfeat_c(const float* __restrict__ patches, const unsigned char* __restrict__ selb,
                           const int* __restrict__ cidx, const int* __restrict__ params,
                           float* __restrict__ mf)
{
  const int count = params[21];
  const int base = blockIdx.x * 256;
  if (base >= count) return;
  const int n = min(256, count - base);
  const int tid = threadIdx.x;
  __shared__ int cl[256];
  __shared__ unsigned char f0s[256], f1s[256];
  if (tid < n){
    int c = cidx[base + tid];
    cl[tid] = c;
    f0s[tid] = selb[c];
    f1s[tid] = selb[T_TOK + c];
  }
  __syncthreads();
  float s00 = 0, s01 = 0, s10 = 0, s11 = 0;
  for (int i = 0; i < n; i++){
    int f0 = f0s[i], f1 = f1s[i];
    if (f0 | f1){
      float2 v = *(const float2*)(patches + (size_t)cl[i] * PDIM + tid * 2);
      if (f0){ s00 += v.x; s01 += v.y; }
      if (f1){ s10 += v.x; s11 += v.y; }
    }
  }
  atomicAdd(&mf[tid * 2],       s00);
  atomicAdd(&mf[tid * 2 + 1],   s01);
  atomicAdd(&mf[512 + tid * 2],     s10);
  atomicAdd(&mf[512 + tid * 2 + 1], s11);
}

// ---------------------------------------------------------------------------
// finalize: all small outputs.
// d_out: [0,2) e_Y_logits | [2] e_Y_hat | [3,5) Y_logits | [5,7) Y_prob |
//        [7] Y_hat | [8,131080) router_logits | [131080] joint | [131081,85) distribute
// ---------------------------------------------------------------------------
__global__ void finalize(const float* __restrict__ bagsum, const float* __restrict__ aggsum,
                         const float* __restrict__ mf, const int* __restrict__ params,
                         const float* __restrict__ Wcls1, const float* __restrict__ Wclf,
                         const float* __restrict__ Wacls, float* __restrict__ dout)
{
  const int lane = threadIdx.x;  // 64 threads
  const int nums0 = params[3], nums1 = params[4], nums2 = params[5];
  const float invT = 1.0f / 65536.0f;
  const float inv0 = 1.0f / (float)(nums0 > 0 ? nums0 : 1);
  const float inv1 = 1.0f / (float)(nums1 > 0 ? nums1 : 1);
  const float totn = (float)(nums0 + nums1 + nums2);
  const float invA = 1.0f / fmaxf(totn, 1.0f);
  float y0 = 0, y1 = 0, a0 = 0, a1 = 0;
  float l00 = 0, l01 = 0, l02 = 0, l10 = 0, l11 = 0, l12 = 0;
  #pragma unroll
  for (int j = 0; j < 8; j++){
    int p = lane * 8 + j;
    float bg = bagsum[p] * invT;
    y0 += bg * Wcls1[p * 2]; y1 += bg * Wcls1[p * 2 + 1];
    float ag = aggsum[p] * invA;
    a0 += ag * Wacls[p * 2]; a1 += ag * Wacls[p * 2 + 1];
    float m0v = mf[p] * inv0;
    l00 += m0v * Wclf[p * 3]; l01 += m0v * Wclf[p * 3 + 1]; l02 += m0v * Wclf[p * 3 + 2];
    float m1v = mf[512 + p] * inv1;
    l10 += m1v * Wclf[1536 + p * 3]; l11 += m1v * Wclf[1536 + p * 3 + 1]; l12 += m1v * Wclf[1536 + p * 3 + 2];
  }
  #pragma unroll
  for (int off = 1; off < 64; off <<= 1){
    y0 += __shfl_xor(y0, off);   y1 += __shfl_xor(y1, off);
    a0 += __shfl_xor(a0, off);   a1 += __shfl_xor(a1, off);
    l00 += __shfl_xor(l00, off); l01 += __shfl_xor(l01, off); l02 += __shfl_xor(l02, off);
    l10 += __shfl_xor(l10, off); l11 += __shfl_xor(l11, off); l12 += __shfl_xor(l12, off);
  }
  if (lane == 0){
    dout[0] = a0; dout[1] = a1;
    dout[2] = (a1 > a0) ? 1.0f : 0.0f;
    dout[3] = y0; dout[4] = y1;
    float mx = fmaxf(y0, y1), e0 = expf(y0 - mx), e1 = expf(y1 - mx), inv = 1.0f / (e0 + e1);
    dout[5] = e0 * inv; dout[6] = e1 * inv;
    dout[7] = (y1 > y0) ? 1.0f : 0.0f;
    float m3 = fmaxf(fmaxf(l00, l01), l02);
    float lse0 = m3 + logf(expf(l00 - m3) + expf(l01 - m3) + expf(l02 - m3));
    float m4 = fmaxf(fmaxf(l10, l11), l12);
    float lse1 = m4 + logf(expf(l10 - m4) + expf(l11 - m4) + expf(l12 - m4));
    dout[131080] = (lse0 - l00) + (lse1 - l11);
    dout[131081] = 65536.0f;
    dout[131082] = (float)nums0;
    dout[131083] = (float)nums1;
    dout[131084] = (float)nums2;
  }
}

// ---------------------------------------------------------------------------
extern "C" void kernel_launch(void* const* d_in, const int* in_sizes, int n_in,
                              void* d_out, int out_size, void* d_ws, size_t ws_size,
                              hipStream_t stream)
{
  const float* X      = (const float*)d_in[0];
  const float* W_t1   = (const float*)d_in[1];
  const float* W_cls1 = (const float*)d_in[2];
  const float* Wg0    = (const float*)d_in[3];
  const float* Wg1    = (const float*)d_in[4];
  const float* Wg2    = (const float*)d_in[5];
  const float* W_clf  = (const float*)d_in[6];
  const float* W_a1   = (const float*)d_in[7];
  const float* W_acls = (const float*)d_in[8];
  float* dout = (float*)d_out;
  char* ws = (char*)d_ws;

  // workspace layout (bytes)
  float*          patches = (float*)         (ws + 0);            // 134217728
  unsigned short* W1th    = (unsigned short*)(ws + 134217728);    // 1048576
  unsigned short* W1tl    = (unsigned short*)(ws + 135266304);    // 1048576
  unsigned short* Wath    = (unsigned short*)(ws + 136314880);    // 524288
  unsigned short* Watl    = (unsigned short*)(ws + 136839168);    // 524288
  unsigned int*   wkey    = (unsigned int*)  (ws + 137363456);    // 262144
  unsigned char*  mask3   = (unsigned char*) (ws + 137625600);    // 65536
  unsigned char*  selb    = (unsigned char*) (ws + 137691136);    // 196608
  int*            cidx    = (int*)           (ws + 137887744);    // 262144
  float*          wgt     = (float*)         (ws + 138149888);    // 262144
  int*            zbase   = (int*)           (ws + 138412032);    // zeroed region
  int*            hist    = zbase;                                // 3*4096
  int*            h2      = zbase + 12288;                        // 3*2048
  int*            params  = zbase + 18432;                        // 64
  float*          bagsum  = (float*)(zbase + 18496);              // 512
  float*          aggsum  = (float*)(zbase + 19008);              // 512
  float*          mf      = (float*)(zbase + 19520);              // 1024  (end 20544)

  prep<<<3153, 256, 0, stream>>>(W_t1, W_a1, W1th, W1tl, Wath, Watl, zbase);

  gemm_split<0><<<dim3(2, 256), 512, 0, stream>>>(
      X, W1th, W1tl, patches, bagsum, nullptr, nullptr, nullptr);

  gates_kernel<<<512, 256, 0, stream>>>(
      patches, Wg0, Wg1, Wg2, dout, wkey, mask3, params, hist);

  find_bucket<<<1, 256, 0, stream>>>(params, hist);
  level2hist<<<dim3(32, 3), 256, 0, stream>>>(params, wkey, mask3, h2);
  find_theta<<<3, 256, 0, stream>>>(params, h2);
  mark_sel<<<dim3(32, 3), 256, 0, stream>>>(params, wkey, mask3, selb);
  compact<<<256, 256, 0, stream>>>(selb, cidx, wgt, params);

  meanfeat_c<<<256, 256, 0, stream>>>(patches, selb, cidx, params, mf);

  gemm_split<1><<<dim3(2, 256), 512, 0, stream>>>(
      patches, Wath, Watl, nullptr, aggsum, cidx, wgt, params);

  finalize<<<1, 64, 0, stream>>>(bagsum, aggsum, mf, params, W_cls1, W_clf, W_acls, dout);
}

// Round 2
// 726.624 us; speedup vs baseline: 1.0540x; 1.0540x over previous
//
#include <hip/hip_runtime.h>
#include <cstdint>
#include <cstddef>

// Problem constants (B=1, S=65536, D=1024, P=512, E=3, C=2)
#define T_TOK 65536
#define DDIM  1024
#define PDIM  512

typedef __attribute__((ext_vector_type(8))) short          shortx8;
typedef __attribute__((ext_vector_type(8))) unsigned short ushortx8;
typedef __attribute__((ext_vector_type(4))) float          floatx4;

__device__ __forceinline__ unsigned short f2bf_rn(float x){
  unsigned int u = __float_as_uint(x);
  unsigned int r = u + 0x7FFFu + ((u >> 16) & 1u);
  return (unsigned short)(r >> 16);
}
__device__ __forceinline__ float bf2f(unsigned short h){
  return __uint_as_float(((unsigned int)h) << 16);
}
// fast tanh, NaN-safe at +-inf of exp
__device__ __forceinline__ float ftanh(float x){
  float ez = __expf(2.f * x);
  return 1.f - 2.f / (ez + 1.f);
}

__device__ __forceinline__ void gload16(const void* g, void* l){
  __builtin_amdgcn_global_load_lds(
      (const __attribute__((address_space(1))) unsigned int*)g,
      (__attribute__((address_space(3))) unsigned int*)l, 16, 0, 0);
}
__device__ __forceinline__ void bar(){
  asm volatile("" ::: "memory");
  __builtin_amdgcn_s_barrier();
  asm volatile("" ::: "memory");
}
#define WAIT_VMC(n) asm volatile("s_waitcnt vmcnt(" #n ")" ::: "memory")
#define WAIT_LGKM0  do { asm volatile("s_waitcnt lgkmcnt(0)" ::: "memory"); \
                         __builtin_amdgcn_sched_barrier(0); } while(0)

// split two float4 (8 consecutive k) into hi/lo bf16 granules (truncation hi,
// exact residual lo) -- matches the MFMA 3-term scheme (hh + lh + hl).
__device__ __forceinline__ void split2(const float4 a, const float4 b,
                                       ushortx8* hi, ushortx8* lo){
  float vs[8] = {a.x, a.y, a.z, a.w, b.x, b.y, b.z, b.w};
  ushortx8 h, l;
  #pragma unroll
  for (int j = 0; j < 8; j++){
    unsigned int u = __float_as_uint(vs[j]);
    float r = vs[j] - __uint_as_float(u & 0xFFFF0000u);
    h[j] = (unsigned short)(u >> 16);
    l[j] = (unsigned short)(__float_as_uint(r) >> 16);
  }
  *hi = h; *lo = l;
}

// ---------------------------------------------------------------------------
// Swizzle: 16B granule g of row r lives at LDS slot  s = g ^ ((r>>1)&3).
// Bank-group of (r, s) = 4*(r&1) + s  ->  for any contiguous 8 lanes of a
// fragment read (16 rows x 4 k-granules) all 8 bank-groups are distinct, and
// the full wave is 8-lanes-per-group balanced: conflict-free ds_read_b128.
// ---------------------------------------------------------------------------

// ---------------------------------------------------------------------------
// prep: zero [hist1 3x4096 | h2 3x2048 | params 64 | bagsum 512 | aggsum 512
//             | mf 1024]  (20544 ints).
// B weights are split to bf16 hi/lo AND re-tiled into the per-(K-tile,
// n-block) inverse-swizzled layout the GEMM's linear global_load_lds staging
// expects:
//   Bt[tb=kt*2+nb][row 0..255][slot s 0..3][e 0..7]
//     = B[nb*256+row][kt*32 + ((s ^ ((row>>1)&3))<<3) + e]  (B[n][k]=W[k][n])
// so LDS granule (row, s) holds k-granule s ^ ((row>>1)&3) -> the swizzled
// ds_read_b128 (slot = quad ^ ((row>>1)&3)) recovers k-granule quad.
// ---------------------------------------------------------------------------
__global__ void prep(const float* __restrict__ Wt1, const float* __restrict__ Wa1,
                     unsigned short* __restrict__ W1th, unsigned short* __restrict__ W1tl,
                     unsigned short* __restrict__ Wath, unsigned short* __restrict__ Watl,
                     int* __restrict__ zbase)
{
  int gid = blockIdx.x * 256 + threadIdx.x;
  if (gid < 20544){ zbase[gid] = 0; return; }
  int i = gid - 20544;
  if (i < 524288){
    int e   = i & 7;
    int g16 = i >> 3;
    int s   = g16 & 3;
    int row = (g16 >> 2) & 255;
    int tb  = g16 >> 10;            // kt*2 + nb, kt < 32
    int nb  = tb & 1, kt = tb >> 1;
    int n = nb * 256 + row;
    int k = kt * 32 + ((s ^ ((row >> 1) & 3)) << 3) + e;
    float x = Wt1[(size_t)k * PDIM + n];
    unsigned short h = f2bf_rn(x);
    W1th[i] = h;
    W1tl[i] = f2bf_rn(x - bf2f(h));
    return;
  }
  i -= 524288;
  if (i < 262144){
    int e   = i & 7;
    int g16 = i >> 3;
    int s   = g16 & 3;
    int row = (g16 >> 2) & 255;
    int tb  = g16 >> 10;            // kt*2 + nb, kt < 16
    int nb  = tb & 1, kt = tb >> 1;
    int n = nb * 256 + row;
    int k = kt * 32 + ((s ^ ((row >> 1) & 3)) << 3) + e;
    float x = Wa1[(size_t)k * PDIM + n];
    unsigned short h = f2bf_rn(x);
    Wath[i] = h;
    Watl[i] = f2bf_rn(x - bf2f(h));
  }
}

// ---------------------------------------------------------------------------
// Split-bf16 GEMM, 256x256 tile, BK=32, 512 threads (8 waves as 2x4;
// per-wave 128x64 output, 8x4 16x16 accumulators).
// 3-phase pipelined K-loop, counted vmcnt (T3+T4), conflict-free swizzle (T2),
// setprio around MFMA clusters (T5):
//   P0: ds_read a-half0 + b-half0 | issue B[t+1] gload_lds     | 24 MFMA
//   P1: ds_read b-half1 | vmcnt(4): A[t+1] regs -> split+ds_write | 24 MFMA
//   P2: ds_read a-half1 | issue A[t+2] reg loads | 48 MFMA | vmcnt(4): B[t+1]
// Issue order (B[t+1] at P0, A[t+2] at P2) keeps 4 younger ops in flight at
// every wait -> vmcnt never drains to 0 in the main loop.
// MODE 0: store tanh(C) (patches); column sums -> atomicAdd colacc (bag).
// MODE 1: rows via cidx (compacted union), weighted column sums (agg).
// ---------------------------------------------------------------------------
template<int MODE>
__global__ __launch_bounds__(512, 2)
void gemm_split(const float* __restrict__ A,
                const unsigned short* __restrict__ Bhg,
                const unsigned short* __restrict__ Blg,
                float* __restrict__ Cout,
                float* __restrict__ colacc,
                const int* __restrict__ cidx,
                const float* __restrict__ wgt,
                const int* __restrict__ params)
{
  constexpr int K  = (MODE == 0) ? 1024 : 512;
  constexpr int NT = K >> 5;

  __shared__ unsigned short AhL[2][8192];
  __shared__ unsigned short AlL[2][8192];
  __shared__ unsigned short BhL[2][8192];
  __shared__ unsigned short BlL[2][8192];
  __shared__ int   cidxl[256];
  __shared__ float wl[256];

  const int tid = threadIdx.x;
  const int d = blockIdx.x + (blockIdx.y << 1);
  // MODE 0: XCD-bijective swizzle (512 % 8 == 0) so both column-blocks of a
  // row-panel land on the same XCD consecutively (A-panel L2 reuse).
  // MODE 1: natural order -- active blocks are the low indices.
  const int lin = (MODE == 0) ? (((d & 7) << 6) + (d >> 3)) : d;
  const int bx = lin & 1, by = lin >> 1;
  const int m0 = by << 8, n0 = bx << 8;

  if (MODE == 1){
    const int count = params[21];
    if (m0 >= count) return;
    if (tid < 256){
      int g = m0 + tid;
      if (g < count){ cidxl[tid] = cidx[g]; wl[tid] = wgt[g]; }
      else          { cidxl[tid] = 0;       wl[tid] = 0.f;   }
    }
    __syncthreads();
  }

  const int lane = tid & 63;
  const int wv   = tid >> 6;
  const int wm   = wv >> 2;          // 0..1  (m wave row)
  const int wn   = wv & 3;           // 0..3  (n wave col)
  const int lr   = lane & 15, quad = lane >> 4;
  const int sq   = (quad ^ ((lr >> 1) & 3)) << 4;   // swizzled 16B slot

  const int abase = (wm * 128 + lr) * 64 + sq;  // + mt*1024
  const int bbase = (wn * 64  + lr) * 64 + sq;  // + nt*1024

  // A staging: thread -> (row, half); 2 threads cover one row's 32 fp32.
  const int rowW = tid >> 1, half = tid & 1;
  const size_t arowg = (MODE == 0) ? (size_t)(m0 + rowW) : (size_t)cidxl[rowW];
  const float* ap = A + arowg * K + half * 16;
  const int rsw = (rowW >> 1) & 3;
  const int wb0 = rowW * 64 + ((( half * 2     ) ^ rsw) << 4);
  const int wb1 = rowW * 64 + ((( half * 2 + 1 ) ^ rsw) << 4);

  floatx4 acc[8][4];
  #pragma unroll
  for (int i = 0; i < 8; i++)
    #pragma unroll
    for (int j = 0; j < 4; j++)
      acc[i][j] = (floatx4){0.f, 0.f, 0.f, 0.f};

  float4 av0, av1, av2, av3;

  // ---- prologue: stage tile 0 into buffer 0; load A[1] regs.
  // Leaves exactly 4 outstanding vmem (A[1] regs) at the first barrier.
  {
    av0 = *(const float4*)(ap + 0);
    av1 = *(const float4*)(ap + 4);
    av2 = *(const float4*)(ap + 8);
    av3 = *(const float4*)(ap + 12);
    const size_t tb = (size_t)bx * 8192;        // kt = 0
    gload16(Bhg + tb + tid * 8,        (char*)BhL[0] + tid * 16);
    gload16(Bhg + tb + 4096 + tid * 8, (char*)BhL[0] + 8192 + tid * 16);
    gload16(Blg + tb + tid * 8,        (char*)BlL[0] + tid * 16);
    gload16(Blg + tb + 4096 + tid * 8, (char*)BlL[0] + 8192 + tid * 16);
    WAIT_VMC(4);                                 // A[0] regs done (B[0] fly)
    ushortx8 h, l;
    split2(av0, av1, &h, &l);
    *(ushortx8*)((char*)AhL[0] + wb0) = h;
    *(ushortx8*)((char*)AlL[0] + wb0) = l;
    split2(av2, av3, &h, &l);
    *(ushortx8*)((char*)AhL[0] + wb1) = h;
    *(ushortx8*)((char*)AlL[0] + wb1) = l;
    {                                            // issue A[1] regs
      const float* apk = ap + ((NT > 1) ? 32 : 0);
      av0 = *(const float4*)(apk);
      av1 = *(const float4*)(apk + 4);
      av2 = *(const float4*)(apk + 8);
      av3 = *(const float4*)(apk + 12);
    }
    WAIT_VMC(4);                                 // B[0] done (A[1] regs fly)
    asm volatile("s_waitcnt lgkmcnt(0)" ::: "memory");  // ds_writes drained
    bar();
  }

  #pragma unroll 2
  for (int t = 0; t < NT; ++t){
    const int cur = t & 1, nxt = cur ^ 1;
    const int knB = (t + 1 < NT) ? (t + 1) : (NT - 1);  // B prefetch tile
    const int knA = (t + 2 < NT) ? (t + 2) : (NT - 1);  // A prefetch tile
    const char* AhC = (const char*)AhL[cur];
    const char* AlC = (const char*)AlL[cur];
    const char* BhC = (const char*)BhL[cur];
    const char* BlC = (const char*)BlL[cur];

    shortx8 aH[4], aL[4], bH0[2], bL0[2], bH1[2], bL1[2];

    // ---- P0: reads a-half0 + b-half0; issue B[t+1] gload_lds -> nxt
    #pragma unroll
    for (int mt = 0; mt < 4; mt++){
      aH[mt] = *(const shortx8*)(AhC + abase + mt * 1024);
      aL[mt] = *(const shortx8*)(AlC + abase + mt * 1024);
    }
    #pragma unroll
    for (int nt = 0; nt < 2; nt++){
      bH0[nt] = *(const shortx8*)(BhC + bbase + nt * 1024);
      bL0[nt] = *(const shortx8*)(BlC + bbase + nt * 1024);
    }
    {
      const size_t tb = (size_t)(knB * 2 + bx) * 8192;
      gload16(Bhg + tb + tid * 8,        (char*)BhL[nxt] + tid * 16);
      gload16(Bhg + tb + 4096 + tid * 8, (char*)BhL[nxt] + 8192 + tid * 16);
      gload16(Blg + tb + tid * 8,        (char*)BlL[nxt] + tid * 16);
      gload16(Blg + tb + 4096 + tid * 8, (char*)BlL[nxt] + 8192 + tid * 16);
    }
    bar();
    WAIT_LGKM0;
    __builtin_amdgcn_s_setprio(1);
    #pragma unroll
    for (int mt = 0; mt < 4; mt++)
      #pragma unroll
      for (int nt = 0; nt < 2; nt++){
        acc[mt][nt] = __builtin_amdgcn_mfma_f32_16x16x32_bf16(aH[mt], bH0[nt], acc[mt][nt], 0, 0, 0);
        acc[mt][nt] = __builtin_amdgcn_mfma_f32_16x16x32_bf16(aL[mt], bH0[nt], acc[mt][nt], 0, 0, 0);
        acc[mt][nt] = __builtin_amdgcn_mfma_f32_16x16x32_bf16(aH[mt], bL0[nt], acc[mt][nt], 0, 0, 0);
      }
    __builtin_amdgcn_s_setprio(0);
    bar();

    // ---- P1: reads b-half1; vmcnt(4) -> A[t+1] regs landed -> split+write
    #pragma unroll
    for (int nt = 0; nt < 2; nt++){
      bH1[nt] = *(const shortx8*)(BhC + bbase + (2 + nt) * 1024);
      bL1[nt] = *(const shortx8*)(BlC + bbase + (2 + nt) * 1024);
    }
    WAIT_VMC(4);                    // A[t+1] regs done (B[t+1] gloads fly)
    {
      ushortx8 h, l;
      split2(av0, av1, &h, &l);
      *(ushortx8*)((char*)AhL[nxt] + wb0) = h;
      *(ushortx8*)((char*)AlL[nxt] + wb0) = l;
      split2(av2, av3, &h, &l);
      *(ushortx8*)((char*)AhL[nxt] + wb1) = h;
      *(ushortx8*)((char*)AlL[nxt] + wb1) = l;
    }
    bar();
    WAIT_LGKM0;                     // drains frag reads AND ds_writes
    __builtin_amdgcn_s_setprio(1);
    #pragma unroll
    for (int mt = 0; mt < 4; mt++)
      #pragma unroll
      for (int nt = 0; nt < 2; nt++){
        acc[mt][2 + nt] = __builtin_amdgcn_mfma_f32_16x16x32_bf16(aH[mt], bH1[nt], acc[mt][2 + nt], 0, 0, 0);
        acc[mt][2 + nt] = __builtin_amdgcn_mfma_f32_16x16x32_bf16(aL[mt], bH1[nt], acc[mt][2 + nt], 0, 0, 0);
        acc[mt][2 + nt] = __builtin_amdgcn_mfma_f32_16x16x32_bf16(aH[mt], bL1[nt], acc[mt][2 + nt], 0, 0, 0);
      }
    __builtin_amdgcn_s_setprio(0);
    bar();

    // ---- P2: reads a-half1; issue A[t+2] regs; 48 MFMA; vmcnt(4) B[t+1]
    #pragma unroll
    for (int mt = 0; mt < 4; mt++){
      aH[mt] = *(const shortx8*)(AhC + abase + (4 + mt) * 1024);
      aL[mt] = *(const shortx8*)(AlC + abase + (4 + mt) * 1024);
    }
    {
      const float* apk = ap + knA * 32;
      av0 = *(const float4*)(apk);
      av1 = *(const float4*)(apk + 4);
      av2 = *(const float4*)(apk + 8);
      av3 = *(const float4*)(apk + 12);
    }
    bar();
    WAIT_LGKM0;
    __builtin_amdgcn_s_setprio(1);
    #pragma unroll
    for (int mt = 0; mt < 4; mt++)
      #pragma unroll
      for (int nt = 0; nt < 2; nt++){
        acc[4 + mt][nt] = __builtin_amdgcn_mfma_f32_16x16x32_bf16(aH[mt], bH0[nt], acc[4 + mt][nt], 0, 0, 0);
        acc[4 + mt][nt] = __builtin_amdgcn_mfma_f32_16x16x32_bf16(aL[mt], bH0[nt], acc[4 + mt][nt], 0, 0, 0);
        acc[4 + mt][nt] = __builtin_amdgcn_mfma_f32_16x16x32_bf16(aH[mt], bL0[nt], acc[4 + mt][nt], 0, 0, 0);
      }
    #pragma unroll
    for (int mt = 0; mt < 4; mt++)
      #pragma unroll
      for (int nt = 0; nt < 2; nt++){
        acc[4 + mt][2 + nt] = __builtin_amdgcn_mfma_f32_16x16x32_bf16(aH[mt], bH1[nt], acc[4 + mt][2 + nt], 0, 0, 0);
        acc[4 + mt][2 + nt] = __builtin_amdgcn_mfma_f32_16x16x32_bf16(aL[mt], bH1[nt], acc[4 + mt][2 + nt], 0, 0, 0);
        acc[4 + mt][2 + nt] = __builtin_amdgcn_mfma_f32_16x16x32_bf16(aH[mt], bL1[nt], acc[4 + mt][2 + nt], 0, 0, 0);
      }
    __builtin_amdgcn_s_setprio(0);
    WAIT_VMC(4);                    // B[t+1] gloads done (A[t+2] regs fly)
    bar();
  }

  // epilogue: tanh, optional store / weighting, column sums -> global atomics
  float csum[4] = {0.f, 0.f, 0.f, 0.f};
  #pragma unroll
  for (int mt = 0; mt < 8; mt++){
    float w0 = 1.f, w1 = 1.f, w2 = 1.f, w3 = 1.f;
    if (MODE == 1){
      const float4 wv4 = *(const float4*)&wl[wm * 128 + mt * 16 + (quad << 2)];
      w0 = wv4.x; w1 = wv4.y; w2 = wv4.z; w3 = wv4.w;
    }
    #pragma unroll
    for (int nt = 0; nt < 4; nt++){
      float t0 = ftanh(acc[mt][nt][0]);
      float t1 = ftanh(acc[mt][nt][1]);
      float t2 = ftanh(acc[mt][nt][2]);
      float t3 = ftanh(acc[mt][nt][3]);
      if (MODE == 0){
        size_t base = (size_t)(m0 + wm * 128 + mt * 16 + (quad << 2)) * PDIM
                    + (n0 + wn * 64 + nt * 16 + lr);
        Cout[base]            = t0;
        Cout[base +     PDIM] = t1;
        Cout[base + 2 * PDIM] = t2;
        Cout[base + 3 * PDIM] = t3;
        csum[nt] += t0 + t1 + t2 + t3;
      } else {
        csum[nt] += t0 * w0 + t1 * w1 + t2 * w2 + t3 * w3;
      }
    }
  }
  #pragma unroll
  for (int nt = 0; nt < 4; nt++){
    float s = csum[nt];
    s += __shfl_xor(s, 16);
    s += __shfl_xor(s, 32);
    if (lane < 16) atomicAdd(&colacc[n0 + wn * 64 + nt * 16 + lane], s);
  }
}

// ---------------------------------------------------------------------------
// gates: per-token 3 gate GEMVs (fp32), router_logits out, w_top0 key, masks,
// per-expert counts, 4096-bin level-1 histograms (mantissa bits [22:11]).
// ---------------------------------------------------------------------------
__global__ void gates_kernel(const float* __restrict__ patches,
                             const float* __restrict__ Wg0,
                             const float* __restrict__ Wg1,
                             const float* __restrict__ Wg2,
                             float* __restrict__ dout,
                             unsigned int* __restrict__ wkey,
                             unsigned char* __restrict__ mask3,
                             int* __restrict__ params,
                             int* __restrict__ hist)
{
  __shared__ int lc[3];
  const int tid = threadIdx.x;
  if (tid < 3) lc[tid] = 0;
  __syncthreads();
  const int lane = tid & 63;
  float wg[3][16];
  const float* Wgp[3] = {Wg0, Wg1, Wg2};
  #pragma unroll
  for (int g = 0; g < 3; g++){
    #pragma unroll
    for (int j = 0; j < 4; j++){
      float4 v = *(const float4*)(Wgp[g] + lane * 16 + j * 4);
      wg[g][j * 4 + 0] = v.x; wg[g][j * 4 + 1] = v.y;
      wg[g][j * 4 + 2] = v.z; wg[g][j * 4 + 3] = v.w;
    }
  }
  const int nw = gridDim.x << 2;
  for (int t = blockIdx.x * 4 + (tid >> 6); t < T_TOK; t += nw){
    const float* row = patches + (size_t)t * PDIM + lane * 8;
    float4 v0 = *(const float4*)row;
    float4 v1 = *(const float4*)(row + 4);
    float x[8] = {v0.x, v0.y, v0.z, v0.w, v1.x, v1.y, v1.z, v1.w};
    float g00 = 0, g01 = 0, g10 = 0, g11 = 0, g20 = 0, g21 = 0;
    #pragma unroll
    for (int j = 0; j < 8; j++){
      g00 += x[j] * wg[0][2 * j]; g01 += x[j] * wg[0][2 * j + 1];
      g10 += x[j] * wg[1][2 * j]; g11 += x[j] * wg[1][2 * j + 1];
      g20 += x[j] * wg[2][2 * j]; g21 += x[j] * wg[2][2 * j + 1];
    }
    #pragma unroll
    for (int off = 1; off < 64; off <<= 1){
      g00 += __shfl_xor(g00, off); g01 += __shfl_xor(g01, off);
      g10 += __shfl_xor(g10, off); g11 += __shfl_xor(g11, off);
      g20 += __shfl_xor(g20, off); g21 += __shfl_xor(g21, off);
    }
    if (lane == 0){
      dout[8 + 2 * t]     = g00;
      dout[8 + 2 * t + 1] = g01;
      int m0 = g01 > g00;
      int m1 = g11 > g10;
      int m2 = g21 > g20;
      mask3[t] = (unsigned char)(m0 | (m1 << 1) | (m2 << 2));
      float d = fabsf(g00 - g01);
      float w = 1.0f / (1.0f + __expf(-d));   // top-1 softmax prob in [0.5,1)
      unsigned int u = __float_as_uint(w);
      u = u < 0x3F000000u ? 0x3F000000u : u;
      u = u > 0x3F7FFFFFu ? 0x3F7FFFFFu : u;
      wkey[t] = u;
      int b = (int)((u >> 11) & 0xFFFu);      // mantissa bits [22:11]
      if (m0){ atomicAdd(&hist[b], 1);         atomicAdd(&lc[0], 1); }
      if (m1){ atomicAdd(&hist[4096 + b], 1);  atomicAdd(&lc[1], 1); }
      if (m2){ atomicAdd(&hist[8192 + b], 1);  atomicAdd(&lc[2], 1); }
    }
  }
  __syncthreads();
  if (tid < 3 && lc[tid]) atomicAdd(&params[tid], lc[tid]);
}

// ---------------------------------------------------------------------------
// find_bucket: nums = floor(cnt*frac) via shifts; locate 12-bit bucket of
// the nums-th largest key (suffix scan over 4096 bins).
// params: [0..2] cnt [3..5] nums [6..8] bucket [9..11] rank-in-bucket
//         [12..14] theta_u [15..17] r_ties [18..20] c_eq [21] compact count
// ---------------------------------------------------------------------------
__global__ void find_bucket(int* __restrict__ params, const int* __restrict__ hist)
{
  __shared__ int cs[256], orig[256];
  __shared__ int selc, selrk;
  const int tid = threadIdx.x;
  for (int e = 0; e < 3; e++){
    int cnt = params[e];
    int shift = (e == 1) ? 1 : 2;              // FRACS 0.25,0.5,0.25 exact
    int nums = cnt >> shift;
    if (nums == 0) nums = cnt;
    if (tid == 0) params[3 + e] = nums;
    __syncthreads();
    if (nums == 0){
      if (tid == 0){ params[6 + e] = -1; params[9 + e] = 0; }
      __syncthreads();
      continue;
    }
    const int* h = hist + e * 4096 + tid * 16;
    int s = 0;
    #pragma unroll
    for (int j = 0; j < 16; j++) s += h[j];
    cs[tid] = s; orig[tid] = s;
    __syncthreads();
    for (int off = 1; off < 256; off <<= 1){
      int v = (tid + off < 256) ? cs[tid + off] : 0;
      __syncthreads();
      cs[tid] += v;
      __syncthreads();
    }
    if (cs[tid] >= nums && (cs[tid] - orig[tid]) < nums){
      selc = tid; selrk = nums - (cs[tid] - orig[tid]);
    }
    __syncthreads();
    if (tid == 0){
      int ch = selc, rk = selrk;
      const int* hh = hist + e * 4096 + ch * 16;
      int acc = 0;
      for (int j = 15; j >= 0; j--){
        int c = hh[j];
        if (acc + c >= rk){ params[6 + e] = ch * 16 + j; params[9 + e] = rk - acc; break; }
        acc += c;
      }
    }
    __syncthreads();
  }
}

// ---------------------------------------------------------------------------
// level2hist: 2048-bin histogram (mantissa bits [10:0]) of keys within the
// chosen bucket. grid (32,3), global atomics.
// ---------------------------------------------------------------------------
__global__ void level2hist(const int* __restrict__ params, const unsigned int* __restrict__ wkey,
                           const unsigned char* __restrict__ mask3, int* __restrict__ h2)
{
  const int e = blockIdx.y;
  const int B = params[6 + e];
  if (B < 0) return;
  const unsigned char bit = (unsigned char)(1u << e);
  const int t0 = blockIdx.x * 2048 + threadIdx.x;
  #pragma unroll
  for (int i = 0; i < 8; i++){
    int t = t0 + i * 256;
    if (mask3[t] & bit){
      unsigned int u = wkey[t];
      if ((int)((u >> 11) & 0xFFFu) == B) atomicAdd(&h2[e * 2048 + (u & 2047u)], 1);
    }
  }
}

// ---------------------------------------------------------------------------
// find_theta: exact threshold key (bucket + sub-bin = all 23 mantissa bits),
// ties-to-take r, tie count c_eq. grid = 3 blocks.
// ---------------------------------------------------------------------------
__global__ void find_theta(int* __restrict__ params, const int* __restrict__ h2)
{
  const int e = blockIdx.x;
  const int tid = threadIdx.x;
  __shared__ int cs[256], orig[256];
  __shared__ int selc;
  int B = params[6 + e], rank = params[9 + e];
  if (B < 0){
    if (tid == 0){ params[12 + e] = (int)0xFFFFFFFFu; params[15 + e] = 0; params[18 + e] = 0; }
    return;
  }
  const int* h = h2 + e * 2048 + tid * 8;
  int s = 0;
  #pragma unroll
  for (int j = 0; j < 8; j++) s += h[j];
  cs[tid] = s; orig[tid] = s;
  __syncthreads();
  for (int off = 1; off < 256; off <<= 1){
    int v = (tid + off < 256) ? cs[tid + off] : 0;
    __syncthreads();
    cs[tid] += v;
    __syncthreads();
  }
  if (cs[tid] >= rank && (cs[tid] - orig[tid]) < rank) selc = tid;
  __syncthreads();
  if (tid == 0){
    int ch = selc;
    int rk = rank - (cs[ch] - orig[ch]);
    const int* hh = h2 + e * 2048 + ch * 8;
    int acc = 0;
    for (int j = 7; j >= 0; j--){
      int c = hh[j];
      if (acc + c >= rk){
        int sub = ch * 8 + j;
        params[12 + e] = (int)(0x3F000000u | ((unsigned)B << 11) | (unsigned)sub);
        params[15 + e] = rk - acc;
        params[18 + e] = c;
        break;
      }
      acc += c;
    }
  }
}

// ---------------------------------------------------------------------------
// mark_sel: sel = mask & (key>theta || (key==theta && tie-rank<r)).
// Fast path when all ties taken; slow stable index-ordered path otherwise.
// ---------------------------------------------------------------------------
__global__ void mark_sel(const int* __restrict__ params, const unsigned int* __restrict__ wkey,
                         const unsigned char* __restrict__ mask3, unsigned char* __restrict__ selb)
{
  const int e = blockIdx.y;
  const int bx = blockIdx.x;
  const int tid = threadIdx.x;
  const unsigned int theta = (unsigned int)params[12 + e];
  const int r = params[15 + e];
  const int ceq = params[18 + e];
  const unsigned char bit = (unsigned char)(1u << e);
  unsigned char* sb = selb + e * T_TOK;
  if (ceq == r){
    int t0 = bx * 2048;
    #pragma unroll
    for (int i = 0; i < 8; i++){
      int t = t0 + i * 256 + tid;
      unsigned char mk = mask3[t] & bit;
      sb[t] = (mk && wkey[t] >= theta) ? 1 : 0;
    }
  } else {
    if (bx) return;
    __shared__ int basec;
    __shared__ int wsum[4];
    if (tid == 0) basec = 0;
    __syncthreads();
    const int lane = tid & 63, w = tid >> 6;
    for (int c = 0; c < 256; c++){
      int t = c * 256 + tid;
      unsigned char mk = mask3[t] & bit;
      unsigned int u = mk ? wkey[t] : 0u;
      bool gt = mk && (u > theta);
      bool eq = mk && (u == theta);
      unsigned long long bal = __ballot(eq);
      if (lane == 0) wsum[w] = __popcll(bal);
      __syncthreads();
      int wbase = 0;
      for (int ww = 0; ww < w; ww++) wbase += wsum[ww];
      int pos = basec + wbase + __popcll(bal & ((1ull << lane) - 1ull));
      sb[t] = (gt || (eq && pos < r)) ? 1 : 0;
      __syncthreads();
      if (tid == 0) basec += wsum[0] + wsum[1] + wsum[2] + wsum[3];
      __syncthreads();
    }
  }
}

// ---------------------------------------------------------------------------
// compact: list of tokens with total_sel>0 (order irrelevant for the sums),
// with float multiplicity weight. Count in params[21].
// ---------------------------------------------------------------------------
__global__ void compact(const unsigned char* __restrict__ selb, int* __restrict__ cidx,
                        float* __restrict__ wgt, int* __restrict__ params)
{
  int t = blockIdx.x * 256 + threadIdx.x;
  int ts = selb[t] + selb[T_TOK + t] + selb[2 * T_TOK + t];
  int lane = threadIdx.x & 63;
  unsigned long long bal = __ballot(ts > 0);
  int base = 0;
  if (lane == 0) base = atomicAdd(&params[21], __popcll(bal));
  base = __shfl(base, 0);
  if (ts){
    int pos = base + __popcll(bal & ((1ull << lane) - 1ull));
    cidx[pos] = t;
    wgt[pos] = (float)ts;
  }
}

// ---------------------------------------------------------------------------
// meanfeat_c: column sums of patches over sel0 / sel1 rows (experts 0,1 only;
// expert 2's mean_feat is unused). Runs over the compacted union list.
// ---------------------------------------------------------------------------
__global__ void meanfeat_c(const float* __restrict__ patches, const unsigned char* __restrict__ selb,
                           const int* __restrict__ cidx, const int* __restrict__ params,
                           float* __restrict__ mf)
{
  const int count = params[21];
  const int base = blockIdx.x * 256;
  if (base >= count) return;
  const int n = min(256, count - base);
  const int tid = threadIdx.x;
  __shared__ int cl[256];
  __shared__ unsigned char f0s[256], f1s[256];
  if (tid < n){
    int c = cidx[base + tid];
    cl[tid] = c;
    f0s[tid] = selb[c];
    f1s[tid] = selb[T_TOK + c];
  }
  __syncthreads();
  float s00 = 0, s01 = 0, s10 = 0, s11 = 0;
  for (int i = 0; i < n; i++){
    int f0 = f0s[i], f1 = f1s[i];
    if (f0 | f1){
      float2 v = *(const float2*)(patches + (size_t)cl[i] * PDIM + tid * 2);
      if (f0){ s00 += v.x; s01 += v.y; }
      if (f1){ s10 += v.x; s11 += v.y; }
    }
  }
  atomicAdd(&mf[tid * 2],       s00);
  atomicAdd(&mf[tid * 2 + 1],   s01);
  atomicAdd(&mf[512 + tid * 2],     s10);
  atomicAdd(&mf[512 + tid * 2 + 1], s11);
}

// ---------------------------------------------------------------------------
// finalize: all small outputs.
// d_out: [0,2) e_Y_logits | [2] e_Y_hat | [3,5) Y_logits | [5,7) Y_prob |
//        [7] Y_hat | [8,131080) router_logits | [131080] joint | [131081,85) distribute
// ---------------------------------------------------------------------------
__global__ void finalize(const float* __restrict__ bagsum, const float* __restrict__ aggsum,
                         const float* __restrict__ mf, const int* __restrict__ params,
                         const float* __restrict__ Wcls1, const float* __restrict__ Wclf,
                         const float* __restrict__ Wacls, float* __restrict__ dout)
{
  const int lane = threadIdx.x;  // 64 threads
  const int nums0 = params[3], nums1 = params[4], nums2 = params[5];
  const float invT = 1.0f / 65536.0f;
  const float inv0 = 1.0f / (float)(nums0 > 0 ? nums0 : 1);
  const float inv1 = 1.0f / (float)(nums1 > 0 ? nums1 : 1);
  const float totn = (float)(nums0 + nums1 + nums2);
  const float invA = 1.0f / fmaxf(totn, 1.0f);
  float y0 = 0, y1 = 0, a0 = 0, a1 = 0;
  float l00 = 0, l01 = 0, l02 = 0, l10 = 0, l11 = 0, l12 = 0;
  #pragma unroll
  for (int j = 0; j < 8; j++){
    int p = lane * 8 + j;
    float bg = bagsum[p] * invT;
    y0 += bg * Wcls1[p * 2]; y1 += bg * Wcls1[p * 2 + 1];
    float ag = aggsum[p] * invA;
    a0 += ag * Wacls[p * 2]; a1 += ag * Wacls[p * 2 + 1];
    float m0v = mf[p] * inv0;
    l00 += m0v * Wclf[p * 3]; l01 += m0v * Wclf[p * 3 + 1]; l02 += m0v * Wclf[p * 3 + 2];
    float m1v = mf[512 + p] * inv1;
    l10 += m1v * Wclf[1536 + p * 3]; l11 += m1v * Wclf[1536 + p * 3 + 1]; l12 += m1v * Wclf[1536 + p * 3 + 2];
  }
  #pragma unroll
  for (int off = 1; off < 64; off <<= 1){
    y0 += __shfl_xor(y0, off);   y1 += __shfl_xor(y1, off);
    a0 += __shfl_xor(a0, off);   a1 += __shfl_xor(a1, off);
    l00 += __shfl_xor(l00, off); l01 += __shfl_xor(l01, off); l02 += __shfl_xor(l02, off);
    l10 += __shfl_xor(l10, off); l11 += __shfl_xor(l11, off); l12 += __shfl_xor(l12, off);
  }
  if (lane == 0){
    dout[0] = a0; dout[1] = a1;
    dout[2] = (a1 > a0) ? 1.0f : 0.0f;
    dout[3] = y0; dout[4] = y1;
    float mx = fmaxf(y0, y1), e0 = expf(y0 - mx), e1 = expf(y1 - mx), inv = 1.0f / (e0 + e1);
    dout[5] = e0 * inv; dout[6] = e1 * inv;
    dout[7] = (y1 > y0) ? 1.0f : 0.0f;
    float m3 = fmaxf(fmaxf(l00, l01), l02);
    float lse0 = m3 + logf(expf(l00 - m3) + expf(l01 - m3) + expf(l02 - m3));
    float m4 = fmaxf(fmaxf(l10, l11), l12);
    float lse1 = m4 + logf(expf(l10 - m4) + expf(l11 - m4) + expf(l12 - m4));
    dout[131080] = (lse0 - l00) + (lse1 - l11);
    dout[131081] = 65536.0f;
    dout[131082] = (float)nums0;
    dout[131083] = (float)nums1;
    dout[131084] = (float)nums2;
  }
}

// ---------------------------------------------------------------------------
extern "C" void kernel_launch(void* const* d_in, const int* in_sizes, int n_in,
                              void* d_out, int out_size, void* d_ws, size_t ws_size,
                              hipStream_t stream)
{
  const float* X      = (const float*)d_in[0];
  const float* W_t1   = (const float*)d_in[1];
  const float* W_cls1 = (const float*)d_in[2];
  const float* Wg0    = (const float*)d_in[3];
  const float* Wg1    = (const float*)d_in[4];
  const float* Wg2    = (const float*)d_in[5];
  const float* W_clf  = (const float*)d_in[6];
  const float* W_a1   = (const float*)d_in[7];
  const float* W_acls = (const float*)d_in[8];
  float* dout = (float*)d_out;
  char* ws = (char*)d_ws;

  // workspace layout (bytes)
  float*          patches = (float*)         (ws + 0);            // 134217728
  unsigned short* W1th    = (unsigned short*)(ws + 134217728);    // 1048576
  unsigned short* W1tl    = (unsigned short*)(ws + 135266304);    // 1048576
  unsigned short* Wath    = (unsigned short*)(ws + 136314880);    // 524288
  unsigned short* Watl    = (unsigned short*)(ws + 136839168);    // 524288
  unsigned int*   wkey    = (unsigned int*)  (ws + 137363456);    // 262144
  unsigned char*  mask3   = (unsigned char*) (ws + 137625600);    // 65536
  unsigned char*  selb    = (unsigned char*) (ws + 137691136);    // 196608
  int*            cidx    = (int*)           (ws + 137887744);    // 262144
  float*          wgt     = (float*)         (ws + 138149888);    // 262144
  int*            zbase   = (int*)           (ws + 138412032);    // zeroed region
  int*            hist    = zbase;                                // 3*4096
  int*            h2      = zbase + 12288;                        // 3*2048
  int*            params  = zbase + 18432;                        // 64
  float*          bagsum  = (float*)(zbase + 18496);              // 512
  float*          aggsum  = (float*)(zbase + 19008);              // 512
  float*          mf      = (float*)(zbase + 19520);              // 1024  (end 20544)

  prep<<<3153, 256, 0, stream>>>(W_t1, W_a1, W1th, W1tl, Wath, Watl, zbase);

  gemm_split<0><<<dim3(2, 256), 512, 0, stream>>>(
      X, W1th, W1tl, patches, bagsum, nullptr, nullptr, nullptr);

  gates_kernel<<<512, 256, 0, stream>>>(
      patches, Wg0, Wg1, Wg2, dout, wkey, mask3, params, hist);

  find_bucket<<<1, 256, 0, stream>>>(params, hist);
  level2hist<<<dim3(32, 3), 256, 0, stream>>>(params, wkey, mask3, h2);
  find_theta<<<3, 256, 0, stream>>>(params, h2);
  mark_sel<<<dim3(32, 3), 256, 0, stream>>>(params, wkey, mask3, selb);
  compact<<<256, 256, 0, stream>>>(selb, cidx, wgt, params);

  meanfeat_c<<<256, 256, 0, stream>>>(patches, selb, cidx, params, mf);

  gemm_split<1><<<dim3(2, 256), 512, 0, stream>>>(
      patches, Wath, Watl, nullptr, aggsum, cidx, wgt, params);

  finalize<<<1, 64, 0, stream>>>(bagsum, aggsum, mf, params, W_cls1, W_clf, W_acls, dout);
}